// Round 1
// baseline (502.012 us; speedup 1.0000x reference)
//
#include <hip/hip_runtime.h>

#define NN 100000   // nodes
#define NE 1000000  // edges
#define FD 64       // feature dim

// ws layout (floats):
//   cnt  : [0,        NN)
//   sum  : [NN,       NN + 64*NN)     (layer-1 neighbor feature sums)
//   p    : [65*NN,    65*NN + 2*NN)   (h @ W2l^T)
//   q    : [67*NN,    67*NN + 2*NN)   (h @ W2r^T + b2)
//   sum2 : [69*NN,    69*NN + 2*NN)   (aggregated p)
// total = 71*NN floats = ~28.4 MB

// ---------------------------------------------------------------------------
// Kernel 1: in-degree counts + write edge_index (as float) to output tail.
__global__ void k_count_edges(const int* __restrict__ ei,
                              float* __restrict__ cnt,
                              float* __restrict__ edge_out) {
    int stride = gridDim.x * blockDim.x;
    for (int e = blockIdx.x * blockDim.x + threadIdx.x; e < 2 * NE; e += stride) {
        int v = ei[e];
        edge_out[e] = (float)v;
        if (e >= NE) atomicAdd(&cnt[v], 1.0f);  // second row = dst
    }
}

// ---------------------------------------------------------------------------
// Kernel 2: sum[dst] += x[src], 64-wide. One wave per edge, contiguous edge
// chunk per wave so the (wave-uniform) edge-index loads hit cached lines.
__global__ __launch_bounds__(256) void k_aggr64(const int* __restrict__ ei,
                                                const float* __restrict__ x,
                                                float* __restrict__ sum) {
    int lane = threadIdx.x & 63;
    int gw = (blockIdx.x * blockDim.x + threadIdx.x) >> 6;
    int nw = (gridDim.x * blockDim.x) >> 6;
    int per = (NE + nw - 1) / nw;
    int e0 = gw * per;
    int e1 = min(e0 + per, NE);
    for (int e = e0; e < e1; ++e) {
        int s = ei[e];
        int d = ei[NE + e];
        float v = x[s * FD + lane];
        atomicAdd(&sum[d * FD + lane], v);
    }
}

// ---------------------------------------------------------------------------
// Kernel 3: per node n (one wave each):
//   h_k = relu(sum[n]@W1l^T[k]/max(cnt,1) + x[n]@W1r^T[k] + b1[k])   (lane k)
//   p[n] = h @ W2l^T   q[n] = h @ W2r^T + b2    (wave reductions)
// Weights register-resident: lane k holds row k of W1l and W1r.
__global__ __launch_bounds__(256) void k_finish(
    const float* __restrict__ x, const float* __restrict__ sum,
    const float* __restrict__ cnt,
    const float* __restrict__ W1l, const float* __restrict__ b1,
    const float* __restrict__ W1r,
    const float* __restrict__ W2l, const float* __restrict__ b2,
    const float* __restrict__ W2r,
    float* __restrict__ p, float* __restrict__ q) {
    int lane = threadIdx.x & 63;
    int gw = (blockIdx.x * blockDim.x + threadIdx.x) >> 6;
    int nw = (gridDim.x * blockDim.x) >> 6;

    float wl[FD], wr[FD];
#pragma unroll
    for (int j = 0; j < FD; j += 4) {
        float4 a = *(const float4*)(W1l + lane * FD + j);
        wl[j] = a.x; wl[j + 1] = a.y; wl[j + 2] = a.z; wl[j + 3] = a.w;
        float4 c = *(const float4*)(W1r + lane * FD + j);
        wr[j] = c.x; wr[j + 1] = c.y; wr[j + 2] = c.z; wr[j + 3] = c.w;
    }
    float b1k = b1[lane];
    float w2l0 = W2l[lane], w2l1 = W2l[FD + lane];
    float w2r0 = W2r[lane], w2r1 = W2r[FD + lane];
    float b20 = b2[0], b21 = b2[1];

    for (int n = gw; n < NN; n += nw) {
        const float4* Sr = (const float4*)(sum + (size_t)n * FD);
        const float4* Xr = (const float4*)(x + (size_t)n * FD);
        float accA = 0.f, accR = 0.f;
#pragma unroll
        for (int j4 = 0; j4 < FD / 4; ++j4) {
            float4 s = Sr[j4];   // wave-uniform broadcast load
            float4 xx = Xr[j4];
            accA += s.x * wl[4 * j4] + s.y * wl[4 * j4 + 1] +
                    s.z * wl[4 * j4 + 2] + s.w * wl[4 * j4 + 3];
            accR += xx.x * wr[4 * j4] + xx.y * wr[4 * j4 + 1] +
                    xx.z * wr[4 * j4 + 2] + xx.w * wr[4 * j4 + 3];
        }
        float c = fmaxf(cnt[n], 1.0f);
        float h = fmaxf(accA / c + accR + b1k, 0.0f);

        float p0 = h * w2l0, p1 = h * w2l1;
        float q0 = h * w2r0, q1 = h * w2r1;
#pragma unroll
        for (int off = 32; off; off >>= 1) {
            p0 += __shfl_xor(p0, off);
            p1 += __shfl_xor(p1, off);
            q0 += __shfl_xor(q0, off);
            q1 += __shfl_xor(q1, off);
        }
        if (lane == 0) {
            *(float2*)(p + 2 * (size_t)n) = make_float2(p0, p1);
            *(float2*)(q + 2 * (size_t)n) = make_float2(q0 + b20, q1 + b21);
        }
    }
}

// ---------------------------------------------------------------------------
// Kernel 4: sum2[dst] += p[src]  (2 floats per edge)
__global__ void k_aggr2(const int* __restrict__ ei,
                        const float* __restrict__ p,
                        float* __restrict__ sum2) {
    int stride = gridDim.x * blockDim.x;
    for (int e = blockIdx.x * blockDim.x + threadIdx.x; e < NE; e += stride) {
        int s = ei[e];
        int d = ei[NE + e];
        float2 v = *(const float2*)(p + 2 * (size_t)s);
        atomicAdd(&sum2[2 * (size_t)d], v.x);
        atomicAdd(&sum2[2 * (size_t)d + 1], v.y);
    }
}

// ---------------------------------------------------------------------------
// Kernel 5: out[n] = sum2[n]/max(cnt,1) + q[n]
__global__ void k_out(const float* __restrict__ sum2,
                      const float* __restrict__ cnt,
                      const float* __restrict__ q,
                      float* __restrict__ out) {
    int stride = gridDim.x * blockDim.x;
    for (int n = blockIdx.x * blockDim.x + threadIdx.x; n < NN; n += stride) {
        float c = fmaxf(cnt[n], 1.0f);
        float2 s = *(const float2*)(sum2 + 2 * (size_t)n);
        float2 qq = *(const float2*)(q + 2 * (size_t)n);
        *(float2*)(out + 2 * (size_t)n) = make_float2(s.x / c + qq.x, s.y / c + qq.y);
    }
}

// ---------------------------------------------------------------------------
extern "C" void kernel_launch(void* const* d_in, const int* in_sizes, int n_in,
                              void* d_out, int out_size, void* d_ws, size_t ws_size,
                              hipStream_t stream) {
    const float* x   = (const float*)d_in[0];
    const int*   ei  = (const int*)d_in[1];
    const float* W1l = (const float*)d_in[2];
    const float* b1  = (const float*)d_in[3];
    const float* W1r = (const float*)d_in[4];
    const float* W2l = (const float*)d_in[5];
    const float* b2  = (const float*)d_in[6];
    const float* W2r = (const float*)d_in[7];

    float* out      = (float*)d_out;      // N*2 floats
    float* edge_out = out + 2 * NN;       // 2*E floats (edge_index as float)

    float* ws   = (float*)d_ws;
    float* cnt  = ws;                      // NN
    float* sum  = ws + NN;                 // 64*NN
    float* p    = ws + (size_t)65 * NN;    // 2*NN
    float* q    = ws + (size_t)67 * NN;    // 2*NN
    float* sum2 = ws + (size_t)69 * NN;    // 2*NN

    // zero accumulators (cnt+sum contiguous)
    hipMemsetAsync(cnt, 0, (size_t)(65 * NN) * sizeof(float), stream);
    hipMemsetAsync(sum2, 0, (size_t)(2 * NN) * sizeof(float), stream);

    k_count_edges<<<2048, 256, 0, stream>>>(ei, cnt, edge_out);
    k_aggr64<<<2048, 256, 0, stream>>>(ei, x, sum);
    k_finish<<<512, 256, 0, stream>>>(x, sum, cnt, W1l, b1, W1r, W2l, b2, W2r, p, q);
    k_aggr2<<<2048, 256, 0, stream>>>(ei, p, sum2);
    k_out<<<512, 256, 0, stream>>>(sum2, cnt, q, out);
}

// Round 2
// 347.244 us; speedup vs baseline: 1.4457x; 1.4457x over previous
//
#include <hip/hip_runtime.h>

#define NN 100000   // nodes
#define NE 1000000  // edges
#define FD 64       // feature dim
#define NBLK 98     // scan blocks: ceil(NN/1024)
#define CH 50000    // node chunk for sum buffer (2 chunks)

// ws layout (4-byte units):
//   deg      : [0, NN)               int   (in-degree)
//   cursor   : [NN, 2NN)             int   (build cursors)
//   rowstart : [2NN, 3NN)            int   (CSR row offsets, exclusive scan of deg)
//   partial  : [3NN, 3NN+128)        int   (scan block sums)
//   csr      : [3NN+128, +NE)        int   (src ids grouped by dst)
//   pq       : [3NN+128+NE, +4NN)    float (p0,p1,q0,q1 per node)
//   sumbuf   : next, CH*64 floats          (layer-1 neighbor sums, per chunk)
// total = 7*NN + 128 + NE + CH*64 = 4.9M * 4B = 19.6 MB

#define OFF_DEG 0
#define OFF_CUR (NN)
#define OFF_ROW (2 * NN)
#define OFF_PAR (3 * NN)
#define OFF_CSR (3 * NN + 128)
#define OFF_PQ  (3 * NN + 128 + NE)
#define OFF_SUM (3 * NN + 128 + NE + 4 * NN)

// ---------------------------------------------------------------------------
// K1: write edge_index (as float) to output tail + in-degree counts (int).
__global__ void k_prep(const int* __restrict__ ei, int* __restrict__ deg,
                       float* __restrict__ edge_out) {
    int stride = gridDim.x * blockDim.x;
    for (int e = blockIdx.x * blockDim.x + threadIdx.x; e < 2 * NE; e += stride) {
        int v = ei[e];
        edge_out[e] = (float)v;
        if (e >= NE) atomicAdd(&deg[v], 1);  // second row = dst
    }
}

// ---------------------------------------------------------------------------
// K2a: per-block (1024-elem) sums of deg -> partial[b]
__global__ __launch_bounds__(256) void k_scanA(const int* __restrict__ deg,
                                               int* __restrict__ partial) {
    __shared__ int lds[256];
    int t = threadIdx.x;
    int base = blockIdx.x * 1024 + t * 4;
    int s_t = 0;
    if (base < NN) {  // NN % 4 == 0, so full int4 is safe
        int4 v = *(const int4*)(deg + base);
        s_t = v.x + v.y + v.z + v.w;
    }
    lds[t] = s_t;
    __syncthreads();
    for (int s = 128; s; s >>= 1) {
        if (t < s) lds[t] += lds[t + s];
        __syncthreads();
    }
    if (t == 0) partial[blockIdx.x] = lds[0];
}

// K2b: block offset (sum of earlier partials) + intra-block exclusive scan
//      -> rowstart[i]
__global__ __launch_bounds__(256) void k_scanB(const int* __restrict__ deg,
                                               const int* __restrict__ partial,
                                               int* __restrict__ rowstart) {
    __shared__ int lds[256];
    int t = threadIdx.x, b = blockIdx.x;
    // block offset = sum partial[0..b-1]   (b <= 97 < 256)
    lds[t] = (t < b && t < NBLK) ? partial[t] : 0;
    __syncthreads();
    for (int s = 128; s; s >>= 1) {
        if (t < s) lds[t] += lds[t + s];
        __syncthreads();
    }
    int bo = lds[0];
    __syncthreads();

    int base = b * 1024 + t * 4;
    int4 v = make_int4(0, 0, 0, 0);
    if (base < NN) v = *(const int4*)(deg + base);
    int s_t = v.x + v.y + v.z + v.w;

    // inclusive Hillis-Steele over 256 per-thread sums
    lds[t] = s_t;
    __syncthreads();
    for (int off = 1; off < 256; off <<= 1) {
        int v2 = lds[t];
        if (t >= off) v2 += lds[t - off];
        __syncthreads();
        lds[t] = v2;
        __syncthreads();
    }
    int excl = lds[t] - s_t;
    if (base < NN) {
        int r = bo + excl;
        int4 out;
        out.x = r;
        out.y = r + v.x;
        out.z = r + v.x + v.y;
        out.w = r + v.x + v.y + v.z;
        *(int4*)(rowstart + base) = out;
    }
}

// ---------------------------------------------------------------------------
// K3: scatter src into CSR slots (int atomics on cursor only).
__global__ void k_build(const int* __restrict__ ei, const int* __restrict__ rowstart,
                        int* __restrict__ cursor, int* __restrict__ csr) {
    int stride = gridDim.x * blockDim.x;
    for (int e = blockIdx.x * blockDim.x + threadIdx.x; e < NE; e += stride) {
        int s = ei[e];
        int d = ei[NE + e];
        int pos = rowstart[d] + atomicAdd(&cursor[d], 1);
        csr[pos] = s;
    }
}

// ---------------------------------------------------------------------------
// K4: per-node neighbor-sum gather (no atomics). One wave per node; lane = feature.
__global__ __launch_bounds__(256) void k_aggr_csr(
    const int* __restrict__ csr, const int* __restrict__ rowstart,
    const int* __restrict__ deg, const float* __restrict__ x,
    float* __restrict__ sumbuf, int n0, int n1) {
    int lane = threadIdx.x & 63;
    int gw = (blockIdx.x * blockDim.x + threadIdx.x) >> 6;
    int n = n0 + gw;
    if (n >= n1) return;
    int rs = rowstart[n];
    int d = deg[n];
    float acc = 0.f;
    int dm = min(d, 64);
    int srcj = (lane < dm) ? csr[rs + lane] : 0;
    for (int j = 0; j < dm; ++j) {
        int s = __shfl(srcj, j);
        acc += x[(size_t)s * FD + lane];
    }
    for (int e = rs + 64; e < rs + d; ++e) {  // deg>64: essentially never, safe
        int s = csr[e];
        acc += x[(size_t)s * FD + lane];
    }
    sumbuf[(size_t)(n - n0) * FD + lane] = acc;
}

// ---------------------------------------------------------------------------
// K5: per node n (one wave each):
//   h_k = relu(sum[n]@W1l^T[k]/max(d,1) + x[n]@W1r^T[k] + b1[k])   (lane k)
//   pq[n] = { h@W2l^T , h@W2r^T + b2 }   (wave reductions, one float4 store)
__global__ __launch_bounds__(256) void k_finish(
    const float* __restrict__ x, const float* __restrict__ sumbuf,
    const int* __restrict__ deg,
    const float* __restrict__ W1l, const float* __restrict__ b1,
    const float* __restrict__ W1r,
    const float* __restrict__ W2l, const float* __restrict__ b2,
    const float* __restrict__ W2r,
    float* __restrict__ pq, int n0, int n1) {
    int lane = threadIdx.x & 63;
    int gw = (blockIdx.x * blockDim.x + threadIdx.x) >> 6;
    int nw = (gridDim.x * blockDim.x) >> 6;

    float wl[FD], wr[FD];
#pragma unroll
    for (int j = 0; j < FD; j += 4) {
        float4 a = *(const float4*)(W1l + lane * FD + j);
        wl[j] = a.x; wl[j + 1] = a.y; wl[j + 2] = a.z; wl[j + 3] = a.w;
        float4 c = *(const float4*)(W1r + lane * FD + j);
        wr[j] = c.x; wr[j + 1] = c.y; wr[j + 2] = c.z; wr[j + 3] = c.w;
    }
    float b1k = b1[lane];
    float w2l0 = W2l[lane], w2l1 = W2l[FD + lane];
    float w2r0 = W2r[lane], w2r1 = W2r[FD + lane];
    float b20 = b2[0], b21 = b2[1];

    for (int n = n0 + gw; n < n1; n += nw) {
        const float4* Sr = (const float4*)(sumbuf + (size_t)(n - n0) * FD);
        const float4* Xr = (const float4*)(x + (size_t)n * FD);
        float accA = 0.f, accR = 0.f;
#pragma unroll
        for (int j4 = 0; j4 < FD / 4; ++j4) {
            float4 s = Sr[j4];   // wave-uniform broadcast load (L1)
            float4 xx = Xr[j4];
            accA += s.x * wl[4 * j4] + s.y * wl[4 * j4 + 1] +
                    s.z * wl[4 * j4 + 2] + s.w * wl[4 * j4 + 3];
            accR += xx.x * wr[4 * j4] + xx.y * wr[4 * j4 + 1] +
                    xx.z * wr[4 * j4 + 2] + xx.w * wr[4 * j4 + 3];
        }
        float invc = 1.0f / (float)max(deg[n], 1);
        float h = fmaxf(accA * invc + accR + b1k, 0.0f);

        float p0 = h * w2l0, p1 = h * w2l1;
        float q0 = h * w2r0, q1 = h * w2r1;
#pragma unroll
        for (int off = 32; off; off >>= 1) {
            p0 += __shfl_xor(p0, off);
            p1 += __shfl_xor(p1, off);
            q0 += __shfl_xor(q0, off);
            q1 += __shfl_xor(q1, off);
        }
        if (lane == 0)
            *(float4*)(pq + 4 * (size_t)n) = make_float4(p0, p1, q0 + b20, q1 + b21);
    }
}

// ---------------------------------------------------------------------------
// K6: layer-2 mean aggregation of p (8B gathers, L2-resident) + final add.
//     Thread per node.
__global__ void k_l2(const int* __restrict__ csr, const int* __restrict__ rowstart,
                     const int* __restrict__ deg, const float* __restrict__ pq,
                     float* __restrict__ out) {
    int n = blockIdx.x * blockDim.x + threadIdx.x;
    if (n >= NN) return;
    int rs = rowstart[n];
    int d = deg[n];
    float a0 = 0.f, a1 = 0.f;
    for (int i = 0; i < d; ++i) {
        int s = csr[rs + i];
        float2 v = *(const float2*)(pq + 4 * (size_t)s);
        a0 += v.x;
        a1 += v.y;
    }
    float inv = 1.0f / (float)max(d, 1);
    float2 q = *(const float2*)(pq + 4 * (size_t)n + 2);
    *(float2*)(out + 2 * (size_t)n) = make_float2(a0 * inv + q.x, a1 * inv + q.y);
}

// ---------------------------------------------------------------------------
extern "C" void kernel_launch(void* const* d_in, const int* in_sizes, int n_in,
                              void* d_out, int out_size, void* d_ws, size_t ws_size,
                              hipStream_t stream) {
    const float* x   = (const float*)d_in[0];
    const int*   ei  = (const int*)d_in[1];
    const float* W1l = (const float*)d_in[2];
    const float* b1  = (const float*)d_in[3];
    const float* W1r = (const float*)d_in[4];
    const float* W2l = (const float*)d_in[5];
    const float* b2  = (const float*)d_in[6];
    const float* W2r = (const float*)d_in[7];

    float* out      = (float*)d_out;   // N*2 floats
    float* edge_out = out + 2 * NN;    // 2*E floats (edge_index as float)

    int*   wsi      = (int*)d_ws;
    int*   deg      = wsi + OFF_DEG;
    int*   cursor   = wsi + OFF_CUR;
    int*   rowstart = wsi + OFF_ROW;
    int*   partial  = wsi + OFF_PAR;
    int*   csr      = wsi + OFF_CSR;
    float* pq       = (float*)d_ws + OFF_PQ;
    float* sumbuf   = (float*)d_ws + OFF_SUM;

    // zero deg + cursor (contiguous)
    hipMemsetAsync(deg, 0, (size_t)(2 * NN) * sizeof(int), stream);

    k_prep<<<2048, 256, 0, stream>>>(ei, deg, edge_out);
    k_scanA<<<NBLK, 256, 0, stream>>>(deg, partial);
    k_scanB<<<NBLK, 256, 0, stream>>>(deg, partial, rowstart);
    k_build<<<2048, 256, 0, stream>>>(ei, rowstart, cursor, csr);

    for (int c = 0; c < 2; ++c) {
        int n0 = c * CH;
        int n1 = min(n0 + CH, NN);
        int waves = n1 - n0;
        k_aggr_csr<<<(waves * 64 + 255) / 256, 256, 0, stream>>>(
            csr, rowstart, deg, x, sumbuf, n0, n1);
        k_finish<<<512, 256, 0, stream>>>(x, sumbuf, deg, W1l, b1, W1r,
                                          W2l, b2, W2r, pq, n0, n1);
    }

    k_l2<<<(NN + 255) / 256, 256, 0, stream>>>(csr, rowstart, deg, pq, out);
}